// Round 12
// baseline (188.802 us; speedup 1.0000x reference)
//
#include <hip/hip_runtime.h>

#define B_ROWS   8192
#define BMASK    8191
#define DIM      128
#define CTILE    64          // columns per tile
#define CHUNK0   20          // z0 col-tiles per block (all chunk lens even)
#define CHUNK1   32          // z1 col-tiles per block
#define NZ1      256         // z1 blocks = 64 panels * (128/CHUNK1)
#define BLK64    16384       // bytes per packed 64-row block (64*128*2)

typedef __attribute__((ext_vector_type(8)))  __bf16 bf16x8;
typedef __attribute__((ext_vector_type(2)))  __bf16 bf16x2;
typedef __attribute__((ext_vector_type(16))) float  f32x16;

// sqrt(log2(e)/0.07) folded symmetrically into both row normalizations.
#define RBSCALE 4.5398159f

__device__ __forceinline__ float fast_exp2(float x) {
#if __has_builtin(__builtin_amdgcn_exp2f)
    return __builtin_amdgcn_exp2f(x);
#else
    return exp2f(x);
#endif
}

// One wave per row: norm -> scale -> bf16 -> k-major packed layout
// packed[row>>6][granule=k/8][row&63][8 bf16]. Block 0 zeroes accumulators.
__global__ __launch_bounds__(256)
void prep_kernel(const float* __restrict__ e1, const float* __restrict__ e2,
                 char* __restrict__ p1, char* __restrict__ p2,
                 float* __restrict__ acc) {
    if (blockIdx.x == 0 && threadIdx.x < 4) acc[threadIdx.x] = 0.f;
    int gw   = (blockIdx.x * 256 + threadIdx.x) >> 6;   // 0..16383
    int lane = threadIdx.x & 63;
    const float* src; char* dst; int row;
    if (gw < B_ROWS) { src = e1; dst = p1; row = gw; }
    else             { src = e2; dst = p2; row = gw - B_ROWS; }
    float2 v = ((const float2*)(src + (size_t)row * DIM))[lane];
    float ss = v.x * v.x + v.y * v.y;
#pragma unroll
    for (int o = 32; o > 0; o >>= 1) ss += __shfl_xor(ss, o);   // butterfly: all lanes get total
    float rb = RBSCALE / sqrtf(ss);
    bf16x2 pk = { (__bf16)(v.x * rb), (__bf16)(v.y * rb) };
    size_t off = (size_t)(row >> 6) * BLK64 + (size_t)(lane >> 2) * 1024
               + (size_t)(row & 63) * 16 + (size_t)(lane & 3) * 4;
    *(bf16x2*)(dst + off) = pk;
}

// Epilogue for one 32x32 accumulator: exp2 + (optional) mask + sum.
// 4-way partial sums break the serial dependent-add chain.
template <bool MASKED>
__device__ __forceinline__ float tile_sum1(const f32x16& a, int ib, int c) {
    float s0 = 0.f, s1 = 0.f, s2 = 0.f, s3 = 0.f;
#pragma unroll
    for (int r = 0; r < 16; ++r) {
        float ev = fast_exp2(a[r]);
        float add;
        if (MASKED) {
            int i = ib + (r & 3) + 8 * (r >> 2);   // m74/m101 C/D row map
            int d = (c - i) & BMASK;               // (c-i) mod B
            add = (d > i) ? ev : 0.f;
        } else {
            add = ev;
        }
        if      ((r & 3) == 0) s0 += add;
        else if ((r & 3) == 1) s1 += add;
        else if ((r & 3) == 2) s2 += add;
        else                   s3 += add;
    }
    return (s0 + s1) + (s2 + s3);
}

#define MFMA32 __builtin_amdgcn_mfma_f32_32x32x16_bf16

// B-fragment load into NAMED register set P (E or O). No arrays, no scratch.
#define LOADB(P, ADDR) do { const char* gp_ = (ADDR);            \
    b##P##0 = *(const bf16x8*)(gp_ +     0);                      \
    b##P##1 = *(const bf16x8*)(gp_ +  2048);                      \
    b##P##2 = *(const bf16x8*)(gp_ +  4096);                      \
    b##P##3 = *(const bf16x8*)(gp_ +  6144);                      \
    b##P##4 = *(const bf16x8*)(gp_ +  8192);                      \
    b##P##5 = *(const bf16x8*)(gp_ + 10240);                      \
    b##P##6 = *(const bf16x8*)(gp_ + 12288);                      \
    b##P##7 = *(const bf16x8*)(gp_ + 14336);                      \
} while (0)

#define BADDR(KK) (Bpack + (size_t)(tile_c0(KK) >> 6) * BLK64 + lane_off)

// 8-MFMA chain for one tile from set P into fresh accumulator R, with T5
// setprio around the matrix cluster.
#define MFMACHAIN(P, R) do {                                     \
    _Pragma("unroll")                                            \
    for (int q_ = 0; q_ < 16; ++q_) R[q_] = 0.f;                 \
    __builtin_amdgcn_s_setprio(1);                               \
    R = MFMA32(af[0], b##P##0, R, 0, 0, 0);                      \
    R = MFMA32(af[1], b##P##1, R, 0, 0, 0);                      \
    R = MFMA32(af[2], b##P##2, R, 0, 0, 0);                      \
    R = MFMA32(af[3], b##P##3, R, 0, 0, 0);                      \
    R = MFMA32(af[4], b##P##4, R, 0, 0, 0);                      \
    R = MFMA32(af[5], b##P##5, R, 0, 0, 0);                      \
    R = MFMA32(af[6], b##P##6, R, 0, 0, 0);                      \
    R = MFMA32(af[7], b##P##7, R, 0, 0, 0);                      \
    __builtin_amdgcn_s_setprio(0);                               \
} while (0)

// LDS-free streaming with DISTANCE-2 register prefetch (T4 analog): two named
// B-sets (bE/bO); each half-iteration consumes one set and re-issues it 2
// tiles ahead -> ~1.5 iterations (~1800cy) of latency cover, compiler emits
// counted vmcnt (r11's dist-1 exposed the full load round-trip every tile:
// occupancy doubled 13->28.5% with zero gain -> per-wave stall, not capacity).
// 512 thr = 8 waves x 32x32 sub-tile; regs ~92 < 128 -> 4 waves/SIMD kept.
// All chunk lengths even (z1=32; z0 cnt=130-2p) -> pairwise loop, no tail.
// 500 blocks @ 2 blocks/CU -> single dispatch round.
__global__ __launch_bounds__(512, 4)
void pair_kernel(const char* __restrict__ P1, const char* __restrict__ P2,
                 float* __restrict__ accg, float* __restrict__ out,
                 int nblocks) {
    __shared__ float red[8];

    const int tid = threadIdx.x;
    const int b   = blockIdx.x;

    // ---- block -> (z, panel p, tile chunk [k0,k1)) ----  (z1 blocks first)
    int z, p, k0, k1;
    if (b < NZ1) {
        z = 1; p = b >> 2; k0 = (b & 3) * CHUNK1; k1 = k0 + CHUNK1;
    } else {
        z = 0;
        int bb0 = b - NZ1, accb = 0;
        p = 0;
        for (;; ++p) {
            int i0t = 128 * p;
            int e1t = (i0t > 128) ? i0t : 128;
            int cnt = 2 + (B_ROWS - e1t) / 64;
            int nb  = (cnt + CHUNK0 - 1) / CHUNK0;
            if (bb0 < accb + nb) {
                int s = bb0 - accb;
                k0 = s * CHUNK0;
                k1 = (k0 + CHUNK0 < cnt) ? (k0 + CHUNK0) : cnt;
                break;
            }
            accb += nb;
        }
    }
    const int i0 = 128 * p;
    const int e1 = (i0 > 128) ? i0 : 128;

    const char* Bpack = (z == 0) ? P1 : P2;

    // tile index k -> column origin c0; masked flag (z=0 only)
    auto tile_c0 = [&](int k) -> int {
        if (z) return k * CTILE;
        int e = (k == 0) ? 64 : e1 + (k - 1) * 64;
        return (i0 + e) & BMASK;
    };
    auto tile_masked = [&](int k) -> bool {
        if (z) return false;
        int e = (k == 0) ? 64 : e1 + (k - 1) * 64;
        return (e < i0 + 256) || (e > 8128);
    };

    const int w  = tid >> 6, lane = tid & 63;
    const int wr = w >> 1, wc = w & 1;     // row-quad [0,4), col-half [0,2)
    const int l  = lane & 31, h = lane >> 5;

    // ---- A fragment -> registers: rows i0 + wr*32 + [0,32), k-major packed ----
    bf16x8 af[8];
    {
        const char* ap = P1 + (size_t)(p * 2 + (wr >> 1)) * BLK64
                            + (size_t)(((wr & 1) << 5) + l) * 16;
#pragma unroll
        for (int s = 0; s < 8; ++s)
            af[s] = *(const bf16x8*)(ap + (size_t)(s * 2 + h) * 1024);
    }

    const int i00 = i0 + wr * 32 + 4 * h;   // epilogue row base for this lane
    const int cb  = wc * 32 + l;            // col offset within tile
    const size_t lane_off = (size_t)cb * 16 + (size_t)h * 1024;

    float sacc = 0.f;
    bf16x8 bE0, bE1, bE2, bE3, bE4, bE5, bE6, bE7;
    bf16x8 bO0, bO1, bO2, bO3, bO4, bO5, bO6, bO7;

    // prologue: 2 tiles in flight (k1-k0 >= 2 always, even)
    LOADB(E, BADDR(k0));
    LOADB(O, BADDR(k0 + 1));

    for (int k = k0; k < k1; k += 2) {
        // ---- even tile: consume bE, re-issue E for k+2 ----
        f32x16 rE;
        MFMACHAIN(E, rE);
        if (k + 2 < k1) LOADB(E, BADDR(k + 2));
        {
            int  c = tile_c0(k) + cb;
            sacc += tile_masked(k) ? tile_sum1<true >(rE, i00, c)
                                   : tile_sum1<false>(rE, i00, c);
        }
        // ---- odd tile: consume bO, re-issue O for k+3 ----
        f32x16 rO;
        MFMACHAIN(O, rO);
        if (k + 3 < k1) LOADB(O, BADDR(k + 3));
        {
            int  c = tile_c0(k + 1) + cb;
            sacc += tile_masked(k + 1) ? tile_sum1<true >(rO, i00, c)
                                       : tile_sum1<false>(rO, i00, c);
        }
    }

#pragma unroll
    for (int o = 32; o > 0; o >>= 1) sacc += __shfl_down(sacc, o);
    if (lane == 0) red[w] = sacc;
    __syncthreads();
    if (tid == 0) {
        float t = (red[0] + red[1]) + (red[2] + red[3])
                + (red[4] + red[5]) + (red[6] + red[7]);
        atomicAdd(&accg[z], t);
        __threadfence();
        unsigned prev = atomicAdd((unsigned*)&accg[2], 1u);
        if (prev == (unsigned)(nblocks - 1)) {
            float l1 = atomicAdd(&accg[0], 0.f);
            float l2 = atomicAdd(&accg[1], 0.f);
            out[0] = -logf(l1 / l2);
        }
    }
}

extern "C" void kernel_launch(void* const* d_in, const int* in_sizes, int n_in,
                              void* d_out, int out_size, void* d_ws, size_t ws_size,
                              hipStream_t stream) {
    (void)in_sizes; (void)n_in; (void)out_size; (void)ws_size;
    const float* e1 = (const float*)d_in[0];
    const float* e2 = (const float*)d_in[1];
    float* out = (float*)d_out;
    char*  ws  = (char*)d_ws;

    float* acc = (float*)ws;                       // 16 B: l1, l2, counter, pad
    char*  p1  = ws + 4096;                        // 2 MB packed E1
    char*  p2  = ws + 4096 + 2097152;              // 2 MB packed E2

    // z0 block count (must match device-side mapping; z1 blocks come first)
    int nz0 = 0;
    for (int p = 0; p < 64; ++p) {
        int i0 = 128 * p;
        int e1t = (i0 > 128) ? i0 : 128;
        int cnt = 2 + (B_ROWS - e1t) / 64;
        nz0 += (cnt + CHUNK0 - 1) / CHUNK0;
    }
    int nblocks = NZ1 + nz0;   // 256 + 244 = 500 <= 512 (2 blocks/CU) -> one round

    prep_kernel<<<dim3(4096), dim3(256), 0, stream>>>(e1, e2, p1, p2, acc);
    pair_kernel<<<dim3(nblocks), dim3(512), 0, stream>>>(p1, p2, acc, out, nblocks);
}

// Round 13
// 109.743 us; speedup vs baseline: 1.7204x; 1.7204x over previous
//
#include <hip/hip_runtime.h>

#define B_ROWS   8192
#define BMASK    8191
#define DIM      128
#define CTILE    64          // columns per tile
#define CHUNK0   10          // z0 col-tiles per block (fine-grained for refill)
#define CHUNK1   16          // z1 col-tiles per block
#define NZ1      512         // z1 blocks = 64 panels * (128/CHUNK1)
#define BLK64    16384       // bytes per packed 64-row block (64*128*2)

typedef __attribute__((ext_vector_type(8)))  __bf16 bf16x8;
typedef __attribute__((ext_vector_type(2)))  __bf16 bf16x2;
typedef __attribute__((ext_vector_type(16))) float  f32x16;

// sqrt(log2(e)/0.07) folded symmetrically into both row normalizations.
#define RBSCALE 4.5398159f

__device__ __forceinline__ float fast_exp2(float x) {
#if __has_builtin(__builtin_amdgcn_exp2f)
    return __builtin_amdgcn_exp2f(x);
#else
    return exp2f(x);
#endif
}

// One wave per row: norm -> scale -> bf16 -> k-major packed layout
// packed[row>>6][granule=k/8][row&63][8 bf16]. Block 0 zeroes accumulators.
__global__ __launch_bounds__(256)
void prep_kernel(const float* __restrict__ e1, const float* __restrict__ e2,
                 char* __restrict__ p1, char* __restrict__ p2,
                 float* __restrict__ acc) {
    if (blockIdx.x == 0 && threadIdx.x < 4) acc[threadIdx.x] = 0.f;
    int gw   = (blockIdx.x * 256 + threadIdx.x) >> 6;   // 0..16383
    int lane = threadIdx.x & 63;
    const float* src; char* dst; int row;
    if (gw < B_ROWS) { src = e1; dst = p1; row = gw; }
    else             { src = e2; dst = p2; row = gw - B_ROWS; }
    float2 v = ((const float2*)(src + (size_t)row * DIM))[lane];
    float ss = v.x * v.x + v.y * v.y;
#pragma unroll
    for (int o = 32; o > 0; o >>= 1) ss += __shfl_xor(ss, o);   // butterfly: all lanes get total
    float rb = RBSCALE / sqrtf(ss);
    bf16x2 pk = { (__bf16)(v.x * rb), (__bf16)(v.y * rb) };
    size_t off = (size_t)(row >> 6) * BLK64 + (size_t)(lane >> 2) * 1024
               + (size_t)(row & 63) * 16 + (size_t)(lane & 3) * 4;
    *(bf16x2*)(dst + off) = pk;
}

// Epilogue for one 64x32 accumulator pair: exp2 + (optional) mask + sum.
// 4-way partial sums break the serial dependent-add chain.
template <bool MASKED>
__device__ __forceinline__ float tile_sum(const f32x16& a0, const f32x16& a1,
                                          int i00, int c) {
    float s0 = 0.f, s1 = 0.f, s2 = 0.f, s3 = 0.f;
#pragma unroll
    for (int g = 0; g < 2; ++g) {
        const f32x16& a = g ? a1 : a0;
        int ib = i00 + g * 32;
#pragma unroll
        for (int r = 0; r < 16; ++r) {
            float ev = fast_exp2(a[r]);
            float add;
            if (MASKED) {
                int i = ib + (r & 3) + 8 * (r >> 2);   // m74/m101 C/D row map
                int d = (c - i) & BMASK;               // (c-i) mod B
                add = (d > i) ? ev : 0.f;
            } else {
                add = ev;
            }
            if      ((r & 3) == 0) s0 += add;
            else if ((r & 3) == 1) s1 += add;
            else if ((r & 3) == 2) s2 += add;
            else                   s3 += add;
        }
    }
    return (s0 + s1) + (s2 + s3);
}

// B-fragment load into NAMED registers (no array, no address-taken -> no scratch).
#define LOADB(kk) do {                                                          \
    const char* gp_ = Bpack + (size_t)(tile_c0(kk) >> 6) * BLK64 + lane_off;    \
    b0 = *(const bf16x8*)(gp_ +     0);                                          \
    b1 = *(const bf16x8*)(gp_ +  2048);                                          \
    b2 = *(const bf16x8*)(gp_ +  4096);                                          \
    b3 = *(const bf16x8*)(gp_ +  6144);                                          \
    b4 = *(const bf16x8*)(gp_ +  8192);                                          \
    b5 = *(const bf16x8*)(gp_ + 10240);                                          \
    b6 = *(const bf16x8*)(gp_ + 12288);                                          \
    b7 = *(const bf16x8*)(gp_ + 14336);                                          \
} while (0)

// r5's proven inner loop (45.4us, VGPR 100, zero spill) with ONE change:
// fine-grained grid (CHUNK1=16, CHUNK0=10 -> ~998 blocks ~= 2 rounds at
// 2 blocks/CU). r5's grid (500 <= 512 capacity) had NO refill: the short z0
// blocks drained at ~60% and every CU ran half-empty for the rest (measured
// OccupancyPercent 13 vs 25 expected). Short blocks + refill keep both block
// slots busy and mix z1/z0 phases per SIMD.
__global__ __launch_bounds__(256, 2)
void pair_kernel(const char* __restrict__ P1, const char* __restrict__ P2,
                 float* __restrict__ accg, float* __restrict__ out,
                 int nblocks) {
    __shared__ float red[4];

    const int tid = threadIdx.x;
    const int b   = blockIdx.x;

    // ---- block -> (z, panel p, tile chunk [k0,k1)) ----  (z1 blocks first)
    int z, p, k0, k1;
    if (b < NZ1) {
        z = 1; p = b >> 3; k0 = (b & 7) * CHUNK1; k1 = k0 + CHUNK1;
    } else {
        z = 0;
        int bb0 = b - NZ1, accb = 0;
        p = 0;
        for (;; ++p) {
            int i0t = 128 * p;
            int e1t = (i0t > 128) ? i0t : 128;
            int cnt = 2 + (B_ROWS - e1t) / 64;
            int nb  = (cnt + CHUNK0 - 1) / CHUNK0;
            if (bb0 < accb + nb) {
                int s = bb0 - accb;
                k0 = s * CHUNK0;
                k1 = (k0 + CHUNK0 < cnt) ? (k0 + CHUNK0) : cnt;
                break;
            }
            accb += nb;
        }
    }
    const int i0 = 128 * p;
    const int e1 = (i0 > 128) ? i0 : 128;

    const char* Bpack = (z == 0) ? P1 : P2;

    // tile index k -> column origin c0; masked flag (z=0 only)
    auto tile_c0 = [&](int k) -> int {
        if (z) return k * CTILE;
        int e = (k == 0) ? 64 : e1 + (k - 1) * 64;
        return (i0 + e) & BMASK;
    };
    auto tile_masked = [&](int k) -> bool {
        if (z) return false;
        int e = (k == 0) ? 64 : e1 + (k - 1) * 64;
        return (e < i0 + 256) || (e > 8128);
    };

    const int w  = tid >> 6, lane = tid & 63;
    const int w2 = w >> 1, wc = w & 1;
    const int l  = lane & 31, h = lane >> 5;

    // ---- A panel -> registers: rows i0 + w2*64 + [0,64), k-major packed ----
    bf16x8 af[2][8];
    {
        const char* ap = P1 + (size_t)(p * 2 + w2) * BLK64;
#pragma unroll
        for (int g = 0; g < 2; ++g)
#pragma unroll
            for (int s = 0; s < 8; ++s)
                af[g][s] = *(const bf16x8*)(ap + (size_t)(s * 2 + h) * 1024
                                               + (size_t)(g * 32 + l) * 16);
    }

    const int i00 = i0 + w2 * 64 + 4 * h;   // epilogue row base for this lane
    const int cb  = wc * 32 + l;            // col offset within tile
    const size_t lane_off = (size_t)cb * 16 + (size_t)h * 1024;

    float sacc = 0.f;
    bf16x8 b0, b1, b2, b3, b4, b5, b6, b7;
    LOADB(k0);

    for (int k = k0; k < k1; ++k) {
        f32x16 r0, r1;
#pragma unroll
        for (int r = 0; r < 16; ++r) { r0[r] = 0.f; r1[r] = 0.f; }

        r0 = __builtin_amdgcn_mfma_f32_32x32x16_bf16(af[0][0], b0, r0, 0, 0, 0);
        r1 = __builtin_amdgcn_mfma_f32_32x32x16_bf16(af[1][0], b0, r1, 0, 0, 0);
        r0 = __builtin_amdgcn_mfma_f32_32x32x16_bf16(af[0][1], b1, r0, 0, 0, 0);
        r1 = __builtin_amdgcn_mfma_f32_32x32x16_bf16(af[1][1], b1, r1, 0, 0, 0);
        r0 = __builtin_amdgcn_mfma_f32_32x32x16_bf16(af[0][2], b2, r0, 0, 0, 0);
        r1 = __builtin_amdgcn_mfma_f32_32x32x16_bf16(af[1][2], b2, r1, 0, 0, 0);
        r0 = __builtin_amdgcn_mfma_f32_32x32x16_bf16(af[0][3], b3, r0, 0, 0, 0);
        r1 = __builtin_amdgcn_mfma_f32_32x32x16_bf16(af[1][3], b3, r1, 0, 0, 0);
        r0 = __builtin_amdgcn_mfma_f32_32x32x16_bf16(af[0][4], b4, r0, 0, 0, 0);
        r1 = __builtin_amdgcn_mfma_f32_32x32x16_bf16(af[1][4], b4, r1, 0, 0, 0);
        r0 = __builtin_amdgcn_mfma_f32_32x32x16_bf16(af[0][5], b5, r0, 0, 0, 0);
        r1 = __builtin_amdgcn_mfma_f32_32x32x16_bf16(af[1][5], b5, r1, 0, 0, 0);
        r0 = __builtin_amdgcn_mfma_f32_32x32x16_bf16(af[0][6], b6, r0, 0, 0, 0);
        r1 = __builtin_amdgcn_mfma_f32_32x32x16_bf16(af[1][6], b6, r1, 0, 0, 0);
        r0 = __builtin_amdgcn_mfma_f32_32x32x16_bf16(af[0][7], b7, r0, 0, 0, 0);
        r1 = __builtin_amdgcn_mfma_f32_32x32x16_bf16(af[1][7], b7, r1, 0, 0, 0);

        int  c = tile_c0(k) + cb;
        bool m = tile_masked(k);

        // issue next tile's loads now (regs free: MFMAs consumed them);
        // pin them before the epilogue so its VALU hides the L2 latency
        if (k + 1 < k1) LOADB(k + 1);
        __builtin_amdgcn_sched_barrier(0);

        sacc += m ? tile_sum<true >(r0, r1, i00, c)
                  : tile_sum<false>(r0, r1, i00, c);
    }

#pragma unroll
    for (int o = 32; o > 0; o >>= 1) sacc += __shfl_down(sacc, o);
    if (lane == 0) red[w] = sacc;
    __syncthreads();
    if (tid == 0) {
        atomicAdd(&accg[z], red[0] + red[1] + red[2] + red[3]);
        __threadfence();
        unsigned prev = atomicAdd((unsigned*)&accg[2], 1u);
        if (prev == (unsigned)(nblocks - 1)) {
            float l1 = atomicAdd(&accg[0], 0.f);
            float l2 = atomicAdd(&accg[1], 0.f);
            out[0] = -logf(l1 / l2);
        }
    }
}

extern "C" void kernel_launch(void* const* d_in, const int* in_sizes, int n_in,
                              void* d_out, int out_size, void* d_ws, size_t ws_size,
                              hipStream_t stream) {
    (void)in_sizes; (void)n_in; (void)out_size; (void)ws_size;
    const float* e1 = (const float*)d_in[0];
    const float* e2 = (const float*)d_in[1];
    float* out = (float*)d_out;
    char*  ws  = (char*)d_ws;

    float* acc = (float*)ws;                       // 16 B: l1, l2, counter, pad
    char*  p1  = ws + 4096;                        // 2 MB packed E1
    char*  p2  = ws + 4096 + 2097152;              // 2 MB packed E2

    // z0 block count (must match device-side mapping; z1 blocks come first)
    int nz0 = 0;
    for (int p = 0; p < 64; ++p) {
        int i0 = 128 * p;
        int e1t = (i0 > 128) ? i0 : 128;
        int cnt = 2 + (B_ROWS - e1t) / 64;
        nz0 += (cnt + CHUNK0 - 1) / CHUNK0;
    }
    int nblocks = NZ1 + nz0;   // 512 + ~486 ~= 998 blocks ~= 2 rounds -> refill

    prep_kernel<<<dim3(4096), dim3(256), 0, stream>>>(e1, e2, p1, p2, acc);
    pair_kernel<<<dim3(nblocks), dim3(256), 0, stream>>>(p1, p2, acc, out, nblocks);
}

// Round 14
// 97.404 us; speedup vs baseline: 1.9383x; 1.1267x over previous
//
#include <hip/hip_runtime.h>

#define B_ROWS   8192
#define BMASK    8191
#define DIM      128
#define CTILE    64          // columns per tile
#define CHUNK0   20          // z0 col-tiles per block
#define CHUNK1   32          // z1 col-tiles per block
#define NZ1      256         // z1 blocks = 64 panels * (128/CHUNK1)
#define BLK64    16384       // bytes per packed 64-row block (64*128*2)

typedef __attribute__((ext_vector_type(8)))  __bf16 bf16x8;
typedef __attribute__((ext_vector_type(2)))  __bf16 bf16x2;
typedef __attribute__((ext_vector_type(16))) float  f32x16;

// sqrt(log2(e)/0.07) folded symmetrically into both row normalizations.
#define RBSCALE 4.5398159f

__device__ __forceinline__ float fast_exp2(float x) {
#if __has_builtin(__builtin_amdgcn_exp2f)
    return __builtin_amdgcn_exp2f(x);
#else
    return exp2f(x);
#endif
}

// One wave per row: norm -> scale -> bf16 -> k-major packed layout
// packed[row>>6][granule=k/8][row&63][8 bf16]. Block 0 zeroes accumulators.
__global__ __launch_bounds__(256)
void prep_kernel(const float* __restrict__ e1, const float* __restrict__ e2,
                 char* __restrict__ p1, char* __restrict__ p2,
                 float* __restrict__ acc) {
    if (blockIdx.x == 0 && threadIdx.x < 4) acc[threadIdx.x] = 0.f;
    int gw   = (blockIdx.x * 256 + threadIdx.x) >> 6;   // 0..16383
    int lane = threadIdx.x & 63;
    const float* src; char* dst; int row;
    if (gw < B_ROWS) { src = e1; dst = p1; row = gw; }
    else             { src = e2; dst = p2; row = gw - B_ROWS; }
    float2 v = ((const float2*)(src + (size_t)row * DIM))[lane];
    float ss = v.x * v.x + v.y * v.y;
#pragma unroll
    for (int o = 32; o > 0; o >>= 1) ss += __shfl_xor(ss, o);   // butterfly: all lanes get total
    float rb = RBSCALE / sqrtf(ss);
    bf16x2 pk = { (__bf16)(v.x * rb), (__bf16)(v.y * rb) };
    size_t off = (size_t)(row >> 6) * BLK64 + (size_t)(lane >> 2) * 1024
               + (size_t)(row & 63) * 16 + (size_t)(lane & 3) * 4;
    *(bf16x2*)(dst + off) = pk;
}

// Epilogue for one 64x32 accumulator pair: exp2 + (optional) mask + sum.
// 4-way partial sums break the serial dependent-add chain.
template <bool MASKED>
__device__ __forceinline__ float tile_sum(const f32x16& a0, const f32x16& a1,
                                          int i00, int c) {
    float s0 = 0.f, s1 = 0.f, s2 = 0.f, s3 = 0.f;
#pragma unroll
    for (int g = 0; g < 2; ++g) {
        const f32x16& a = g ? a1 : a0;
        int ib = i00 + g * 32;
#pragma unroll
        for (int r = 0; r < 16; ++r) {
            float ev = fast_exp2(a[r]);
            float add;
            if (MASKED) {
                int i = ib + (r & 3) + 8 * (r >> 2);   // m74/m101 C/D row map
                int d = (c - i) & BMASK;               // (c-i) mod B
                add = (d > i) ? ev : 0.f;
            } else {
                add = ev;
            }
            if      ((r & 3) == 0) s0 += add;
            else if ((r & 3) == 1) s1 += add;
            else if ((r & 3) == 2) s2 += add;
            else                   s3 += add;
        }
    }
    return (s0 + s1) + (s2 + s3);
}

#define MFMA32 __builtin_amdgcn_mfma_f32_32x32x16_bf16

// B-fragment load into NAMED registers (no array, no address-taken -> no scratch).
#define LOADB(kk) do {                                                          \
    const char* gp_ = Bpack + (size_t)(tile_c0(kk) >> 6) * BLK64 + lane_off;    \
    b0 = *(const bf16x8*)(gp_ +     0);                                          \
    b1 = *(const bf16x8*)(gp_ +  2048);                                          \
    b2 = *(const bf16x8*)(gp_ +  4096);                                          \
    b3 = *(const bf16x8*)(gp_ +  6144);                                          \
    b4 = *(const bf16x8*)(gp_ +  8192);                                          \
    b5 = *(const bf16x8*)(gp_ + 10240);                                          \
    b6 = *(const bf16x8*)(gp_ + 12288);                                          \
    b7 = *(const bf16x8*)(gp_ + 14336);                                          \
} while (0)

// r5's proven structure (45.4us, VGPR 100, zero spill) with ONE change: the
// next tile's B-loads are interleaved INTO the MFMA chain -- each b_s reloads
// for tile k+1 right after the MFMA pair that consumes it (in-order issue
// makes the WAR safe; compiler renames a few regs). Cover per load grows from
// ~450cy (epilogue only -- r5 issued all loads after the 512cy chain) to
// ~700-900cy, and vmem issues during the matrix phase. r5's cycle accounting:
// pipes busy only 45% of the 2292cy/tile slot; ~1250cy/tile is exposed load
// latency on BOTH waves -- the one residual no schedule variant has attacked
// within the no-spill envelope.
__global__ __launch_bounds__(256, 2)
void pair_kernel(const char* __restrict__ P1, const char* __restrict__ P2,
                 float* __restrict__ accg, float* __restrict__ out,
                 int nblocks) {
    __shared__ float red[4];

    const int tid = threadIdx.x;
    const int b   = blockIdx.x;

    // ---- block -> (z, panel p, tile chunk [k0,k1)) ----  (z1 blocks first)
    int z, p, k0, k1;
    if (b < NZ1) {
        z = 1; p = b >> 2; k0 = (b & 3) * CHUNK1; k1 = k0 + CHUNK1;
    } else {
        z = 0;
        int bb0 = b - NZ1, accb = 0;
        p = 0;
        for (;; ++p) {
            int i0t = 128 * p;
            int e1t = (i0t > 128) ? i0t : 128;
            int cnt = 2 + (B_ROWS - e1t) / 64;
            int nb  = (cnt + CHUNK0 - 1) / CHUNK0;
            if (bb0 < accb + nb) {
                int s = bb0 - accb;
                k0 = s * CHUNK0;
                k1 = (k0 + CHUNK0 < cnt) ? (k0 + CHUNK0) : cnt;
                break;
            }
            accb += nb;
        }
    }
    const int i0 = 128 * p;
    const int e1 = (i0 > 128) ? i0 : 128;

    const char* Bpack = (z == 0) ? P1 : P2;

    // tile index k -> column origin c0; masked flag (z=0 only)
    auto tile_c0 = [&](int k) -> int {
        if (z) return k * CTILE;
        int e = (k == 0) ? 64 : e1 + (k - 1) * 64;
        return (i0 + e) & BMASK;
    };
    auto tile_masked = [&](int k) -> bool {
        if (z) return false;
        int e = (k == 0) ? 64 : e1 + (k - 1) * 64;
        return (e < i0 + 256) || (e > 8128);
    };

    const int w  = tid >> 6, lane = tid & 63;
    const int w2 = w >> 1, wc = w & 1;
    const int l  = lane & 31, h = lane >> 5;

    // ---- A panel -> registers: rows i0 + w2*64 + [0,64), k-major packed ----
    bf16x8 af[2][8];
    {
        const char* ap = P1 + (size_t)(p * 2 + w2) * BLK64;
#pragma unroll
        for (int g = 0; g < 2; ++g)
#pragma unroll
            for (int s = 0; s < 8; ++s)
                af[g][s] = *(const bf16x8*)(ap + (size_t)(s * 2 + h) * 1024
                                               + (size_t)(g * 32 + l) * 16);
    }

    const int i00 = i0 + w2 * 64 + 4 * h;   // epilogue row base for this lane
    const int cb  = wc * 32 + l;            // col offset within tile
    const size_t lane_off = (size_t)cb * 16 + (size_t)h * 1024;

    float sacc = 0.f;
    bf16x8 b0, b1, b2, b3, b4, b5, b6, b7;
    LOADB(k0);

    for (int k = k0; k < k1; ++k) {
        // current tile's metadata BEFORE b-regs are recycled
        int  c = tile_c0(k) + cb;
        bool m = tile_masked(k);
        // next-tile load base (clamped on last iter: harmless re-read, unused)
        int kn = (k + 1 < k1) ? (k + 1) : k;
        const char* gn = Bpack + (size_t)(tile_c0(kn) >> 6) * BLK64 + lane_off;

        f32x16 r0, r1;
#pragma unroll
        for (int r = 0; r < 16; ++r) { r0[r] = 0.f; r1[r] = 0.f; }

        // MFMA chain with next-tile loads interleaved: reload b_s right after
        // the MFMA pair consuming it -> vmem issues under the matrix phase.
        r0 = MFMA32(af[0][0], b0, r0, 0, 0, 0);
        r1 = MFMA32(af[1][0], b0, r1, 0, 0, 0);
        b0 = *(const bf16x8*)(gn +     0);
        r0 = MFMA32(af[0][1], b1, r0, 0, 0, 0);
        r1 = MFMA32(af[1][1], b1, r1, 0, 0, 0);
        b1 = *(const bf16x8*)(gn +  2048);
        r0 = MFMA32(af[0][2], b2, r0, 0, 0, 0);
        r1 = MFMA32(af[1][2], b2, r1, 0, 0, 0);
        b2 = *(const bf16x8*)(gn +  4096);
        r0 = MFMA32(af[0][3], b3, r0, 0, 0, 0);
        r1 = MFMA32(af[1][3], b3, r1, 0, 0, 0);
        b3 = *(const bf16x8*)(gn +  6144);
        r0 = MFMA32(af[0][4], b4, r0, 0, 0, 0);
        r1 = MFMA32(af[1][4], b4, r1, 0, 0, 0);
        b4 = *(const bf16x8*)(gn +  8192);
        r0 = MFMA32(af[0][5], b5, r0, 0, 0, 0);
        r1 = MFMA32(af[1][5], b5, r1, 0, 0, 0);
        b5 = *(const bf16x8*)(gn + 10240);
        r0 = MFMA32(af[0][6], b6, r0, 0, 0, 0);
        r1 = MFMA32(af[1][6], b6, r1, 0, 0, 0);
        b6 = *(const bf16x8*)(gn + 12288);
        r0 = MFMA32(af[0][7], b7, r0, 0, 0, 0);
        r1 = MFMA32(af[1][7], b7, r1, 0, 0, 0);
        b7 = *(const bf16x8*)(gn + 14336);

        // keep loads above the epilogue (don't let the scheduler sink them)
        __builtin_amdgcn_sched_barrier(0);

        sacc += m ? tile_sum<true >(r0, r1, i00, c)
                  : tile_sum<false>(r0, r1, i00, c);
    }

#pragma unroll
    for (int o = 32; o > 0; o >>= 1) sacc += __shfl_down(sacc, o);
    if (lane == 0) red[w] = sacc;
    __syncthreads();
    if (tid == 0) {
        atomicAdd(&accg[z], red[0] + red[1] + red[2] + red[3]);
        __threadfence();
        unsigned prev = atomicAdd((unsigned*)&accg[2], 1u);
        if (prev == (unsigned)(nblocks - 1)) {
            float l1 = atomicAdd(&accg[0], 0.f);
            float l2 = atomicAdd(&accg[1], 0.f);
            out[0] = -logf(l1 / l2);
        }
    }
}

extern "C" void kernel_launch(void* const* d_in, const int* in_sizes, int n_in,
                              void* d_out, int out_size, void* d_ws, size_t ws_size,
                              hipStream_t stream) {
    (void)in_sizes; (void)n_in; (void)out_size; (void)ws_size;
    const float* e1 = (const float*)d_in[0];
    const float* e2 = (const float*)d_in[1];
    float* out = (float*)d_out;
    char*  ws  = (char*)d_ws;

    float* acc = (float*)ws;                       // 16 B: l1, l2, counter, pad
    char*  p1  = ws + 4096;                        // 2 MB packed E1
    char*  p2  = ws + 4096 + 2097152;              // 2 MB packed E2

    // z0 block count (must match device-side mapping; z1 blocks come first)
    int nz0 = 0;
    for (int p = 0; p < 64; ++p) {
        int i0 = 128 * p;
        int e1t = (i0 > 128) ? i0 : 128;
        int cnt = 2 + (B_ROWS - e1t) / 64;
        nz0 += (cnt + CHUNK0 - 1) / CHUNK0;
    }
    int nblocks = NZ1 + nz0;   // 256 + 244 = 500 <= 512 (2 blocks/CU) -> one round

    prep_kernel<<<dim3(4096), dim3(256), 0, stream>>>(e1, e2, p1, p2, acc);
    pair_kernel<<<dim3(nblocks), dim3(256), 0, stream>>>(p1, p2, acc, out, nblocks);
}